// Round 1
// 3095.882 us; speedup vs baseline: 1.0556x; 1.0556x over previous
//
#include <hip/hip_runtime.h>

#define N_USER 100000
#define N_ITEM 50000
#define N_NODES 150000
#define DIM 64
#define N_NNZ 6400000
#define N_LAYER 3
#define TOTAL_EDGES (2 * N_NNZ)   // each nnz contributes to one user row and one item row

// Two-phase counting sort parameters: bucket = node >> NODE_SHIFT
#define NODE_SHIFT 4
#define NODES_PER_BUCKET 16                       // 1 << NODE_SHIFT
#define NBUCKETS (N_NODES / NODES_PER_BUCKET)     // 9375, divides exactly
#define PAD 16                                    // ints per cursor slot (64B line)

// ---------------------------------------------------------------------------
// Phase 0: coarse bucket histogram (padded counters, one per cache line)
// ---------------------------------------------------------------------------
__global__ __launch_bounds__(256) void bucket_hist_kernel(
    const int* __restrict__ rows,
    const int* __restrict__ cols,
    int* __restrict__ padded)   // [NBUCKETS*PAD], pre-zeroed, count at [b*PAD]
{
    int e = blockIdx.x * blockDim.x + threadIdx.x;
    if (e >= N_NNZ) return;
    const int r = rows[e];
    const int c = N_USER + cols[e];
    atomicAdd(&padded[(r >> NODE_SHIFT) * PAD], 1);
    atomicAdd(&padded[(c >> NODE_SHIFT) * PAD], 1);
}

// ---------------------------------------------------------------------------
// Exclusive scan over NBUCKETS strided-padded counts (single block).
// Writes the exclusive scan back into padded[b*PAD] (becomes the bin cursor)
// and a compact copy into base[b]; base[NBUCKETS] = TOTAL_EDGES.
// ---------------------------------------------------------------------------
__global__ __launch_bounds__(1024) void bucket_scan_kernel(
    int* __restrict__ padded,
    int* __restrict__ base)
{
    __shared__ int wsum[16];
    __shared__ int woff[16];
    __shared__ int carry_s;
    if (threadIdx.x == 0) carry_s = 0;
    __syncthreads();

    const int lane = threadIdx.x & 63;
    const int wid  = threadIdx.x >> 6;

    for (int b0 = 0; b0 < NBUCKETS; b0 += 1024) {
        int b = b0 + (int)threadIdx.x;
        int v = (b < NBUCKETS) ? padded[b * PAD] : 0;

        int incl = v;
        #pragma unroll
        for (int off = 1; off < 64; off <<= 1) {
            int t = __shfl_up(incl, off, 64);
            if (lane >= off) incl += t;
        }
        if (lane == 63) wsum[wid] = incl;
        __syncthreads();

        if (threadIdx.x == 0) {
            int s = carry_s;
            #pragma unroll
            for (int w = 0; w < 16; ++w) { woff[w] = s; s += wsum[w]; }
            carry_s = s;
        }
        __syncthreads();

        if (b < NBUCKETS) {
            int excl = woff[wid] + incl - v;
            padded[b * PAD] = excl;   // becomes bin cursor
            base[b] = excl;           // compact bases for phase 2
        }
        __syncthreads();
    }
    if (threadIdx.x == 0) base[NBUCKETS] = TOTAL_EDGES;
}

// ---------------------------------------------------------------------------
// Phase 1: bin edges into coarse buckets. Writes are atomic-cursor-ordered,
// i.e. dense per bucket -> the ~9375-line write frontier merges in L2.
// Record: x = (node_low4 << 18) | src  (src < 150000 < 2^18), y = val bits.
// ---------------------------------------------------------------------------
__global__ __launch_bounds__(256) void bin_kernel(
    const int* __restrict__ rows,
    const int* __restrict__ cols,
    const float* __restrict__ vals,
    int* __restrict__ padded,      // bucket cursors at [b*PAD]
    int2* __restrict__ binned)     // [TOTAL_EDGES]
{
    int e = blockIdx.x * blockDim.x + threadIdx.x;
    if (e >= N_NNZ) return;
    const int r  = rows[e];
    const int c  = N_USER + cols[e];
    const int vb = __float_as_int(vals[e]);

    // user row r gathers from item node c
    int p1 = atomicAdd(&padded[(r >> NODE_SHIFT) * PAD], 1);
    binned[p1] = make_int2(((r & (NODES_PER_BUCKET - 1)) << 18) | c, vb);
    // item row c gathers from user node r
    int p2 = atomicAdd(&padded[(c >> NODE_SHIFT) * PAD], 1);
    binned[p2] = make_int2(((c & (NODES_PER_BUCKET - 1)) << 18) | r, vb);
}

// ---------------------------------------------------------------------------
// Phase 2: per-bucket local scatter. One block per bucket (~1.4K records,
// ~11 KB window -> fully L2-resident). Also derives per-node CSR offsets
// locally (LDS histogram + 16-wide scan), eliminating the global node
// histogram / 150K scan / global cursor atomics entirely.
// ---------------------------------------------------------------------------
__global__ __launch_bounds__(256) void bucket_scatter_kernel(
    const int* __restrict__ base,      // [NBUCKETS+1]
    const int2* __restrict__ binned,
    int* __restrict__ offsets,         // [N_NODES+1] (written here)
    int2* __restrict__ edges)          // [TOTAL_EDGES] final (src, val)
{
    const int b   = blockIdx.x;
    const int tid = threadIdx.x;
    const int beg = base[b];
    const int end = base[b + 1];

    __shared__ int cnt[NODES_PER_BUCKET];
    __shared__ int ofs[NODES_PER_BUCKET];
    if (tid < NODES_PER_BUCKET) cnt[tid] = 0;
    __syncthreads();

    for (int i = beg + tid; i < end; i += blockDim.x) {
        atomicAdd(&cnt[binned[i].x >> 18], 1);
    }
    __syncthreads();

    if (tid == 0) {
        int s = 0;
        #pragma unroll
        for (int j = 0; j < NODES_PER_BUCKET; ++j) { ofs[j] = s; s += cnt[j]; }
    }
    __syncthreads();

    if (tid < NODES_PER_BUCKET) {
        offsets[b * NODES_PER_BUCKET + tid] = beg + ofs[tid];
        cnt[tid] = ofs[tid];   // reuse as intra-bucket cursor
    }
    if (b == 0 && tid == 0) offsets[N_NODES] = TOTAL_EDGES;
    __syncthreads();

    // second read of binned hits L2 (just fetched by this block)
    for (int i = beg + tid; i < end; i += blockDim.x) {
        int2 rec = binned[i];
        int nl   = rec.x >> 18;
        int src  = rec.x & 0x3FFFF;
        int p    = beg + atomicAdd(&cnt[nl], 1);
        edges[p] = make_int2(src, rec.y);
    }
}

// ---------------------------------------------------------------------------
// Gather propagation: one wave per output row, lane = dim. Fused residual.
// ---------------------------------------------------------------------------
__global__ __launch_bounds__(256) void gather_kernel(
    const int* __restrict__ offsets,
    const int2* __restrict__ edges,
    const float* __restrict__ lat_prev,
    float* __restrict__ gcn_l,
    float* __restrict__ lat_l)
{
    const int gtid = blockIdx.x * blockDim.x + threadIdx.x;
    const int node = gtid >> 6;
    const int lane = gtid & 63;
    if (node >= N_NODES) return;

    const int beg = offsets[node];
    const int end = offsets[node + 1];

    float acc = 0.f;
    int e = beg;
    for (; e + 4 <= end; e += 4) {
        int2 e0 = edges[e];
        int2 e1 = edges[e + 1];
        int2 e2 = edges[e + 2];
        int2 e3 = edges[e + 3];
        float x0 = lat_prev[(size_t)e0.x * DIM + lane];
        float x1 = lat_prev[(size_t)e1.x * DIM + lane];
        float x2 = lat_prev[(size_t)e2.x * DIM + lane];
        float x3 = lat_prev[(size_t)e3.x * DIM + lane];
        acc += __int_as_float(e0.y) * x0;
        acc += __int_as_float(e1.y) * x1;
        acc += __int_as_float(e2.y) * x2;
        acc += __int_as_float(e3.y) * x3;
    }
    for (; e < end; ++e) {
        int2 ee = edges[e];
        acc += __int_as_float(ee.y) * lat_prev[(size_t)ee.x * DIM + lane];
    }

    const size_t o = (size_t)node * DIM + lane;
    gcn_l[o] = acc;
    lat_l[o] = lat_prev[o] + acc;
}

// ---------------------------------------------------------------------------
// Fallback tier 2: previous-round single-pass CSR build (random scatter fill)
// ---------------------------------------------------------------------------
__global__ __launch_bounds__(256) void histogram_kernel(
    const int* __restrict__ rows,
    const int* __restrict__ cols,
    int* __restrict__ counts)
{
    int e = blockIdx.x * blockDim.x + threadIdx.x;
    if (e >= N_NNZ) return;
    atomicAdd(&counts[rows[e]], 1);
    atomicAdd(&counts[N_USER + cols[e]], 1);
}

__global__ __launch_bounds__(1024) void scan_kernel(int* __restrict__ data, int n)
{
    __shared__ int wsum[16];
    __shared__ int woff[16];
    __shared__ int carry_s;
    if (threadIdx.x == 0) carry_s = 0;
    __syncthreads();

    const int lane = threadIdx.x & 63;
    const int wid  = threadIdx.x >> 6;

    for (int bse = 0; bse < n; bse += 1024) {
        int i = bse + (int)threadIdx.x;
        int v = (i < n) ? data[i] : 0;

        int incl = v;
        #pragma unroll
        for (int off = 1; off < 64; off <<= 1) {
            int t = __shfl_up(incl, off, 64);
            if (lane >= off) incl += t;
        }
        if (lane == 63) wsum[wid] = incl;
        __syncthreads();

        if (threadIdx.x == 0) {
            int s = carry_s;
            #pragma unroll
            for (int w = 0; w < 16; ++w) { woff[w] = s; s += wsum[w]; }
            carry_s = s;
        }
        __syncthreads();

        if (i < n) data[i] = woff[wid] + incl - v;
        __syncthreads();
    }
}

__global__ __launch_bounds__(256) void fill_kernel(
    const int* __restrict__ rows,
    const int* __restrict__ cols,
    const float* __restrict__ vals,
    int* __restrict__ cursor,
    int2* __restrict__ edges)
{
    int e = blockIdx.x * blockDim.x + threadIdx.x;
    if (e >= N_NNZ) return;
    const int r = rows[e];
    const int c = cols[e];
    const int vb = __float_as_int(vals[e]);
    int pu = atomicAdd(&cursor[r], 1);
    edges[pu] = make_int2(N_USER + c, vb);
    int pi = atomicAdd(&cursor[N_USER + c], 1);
    edges[pi] = make_int2(r, vb);
}

// ---------------------------------------------------------------------------
// Fallback tier 3: atomic scatter
// ---------------------------------------------------------------------------
__global__ __launch_bounds__(256) void scatter_kernel(
    const int* __restrict__ rows,
    const int* __restrict__ cols,
    const float* __restrict__ vals,
    const float* __restrict__ lat_prev,
    float* __restrict__ gcn_out)
{
    const int gtid = blockIdx.x * blockDim.x + threadIdx.x;
    const int edge = gtid >> 6;
    const int lane = gtid & 63;
    if (edge >= N_NNZ) return;
    const int r = rows[edge];
    const int c = cols[edge];
    const float v = vals[edge];
    atomicAdd(&gcn_out[(size_t)r * DIM + lane],
              v * lat_prev[(size_t)(N_USER + c) * DIM + lane]);
    atomicAdd(&gcn_out[(size_t)(N_USER + c) * DIM + lane],
              v * lat_prev[(size_t)r * DIM + lane]);
}

__global__ __launch_bounds__(256) void residual_add_kernel(
    const float4* __restrict__ a,
    const float4* __restrict__ b,
    float4* __restrict__ out,
    int n4)
{
    int i = blockIdx.x * blockDim.x + threadIdx.x;
    if (i < n4) {
        float4 av = a[i], bv = b[i];
        out[i] = make_float4(av.x + bv.x, av.y + bv.y, av.z + bv.z, av.w + bv.w);
    }
}

extern "C" void kernel_launch(void* const* d_in, const int* in_sizes, int n_in,
                              void* d_out, int out_size, void* d_ws, size_t ws_size,
                              hipStream_t stream) {
    const int*   rows   = (const int*)d_in[0];
    const int*   cols   = (const int*)d_in[1];
    const float* vals   = (const float*)d_in[2];
    const float* embeds = (const float*)d_in[3];

    float* out = (float*)d_out;
    const size_t N = (size_t)N_NODES * DIM;   // floats per snapshot

    float* lats = out;            // [4][N_NODES][DIM]
    float* gcn  = out + 4 * N;    // [4][N_NODES][DIM]

    // lats[0] = gcn[0] = embeds
    hipMemcpyAsync(lats, embeds, N * sizeof(float), hipMemcpyDeviceToDevice, stream);
    hipMemcpyAsync(gcn,  embeds, N * sizeof(float), hipMemcpyDeviceToDevice, stream);

    const size_t edges_bytes = (size_t)TOTAL_EDGES * sizeof(int2);   // 102,400,000

    // ---- Tier-1 workspace layout: two-phase counting sort ----
    const size_t padded_bytes = (size_t)NBUCKETS * PAD * sizeof(int);        // 600,000
    const size_t base_off     = (padded_bytes + 15) & ~(size_t)15;
    const size_t base_bytes   = (size_t)(NBUCKETS + 1) * sizeof(int);        // 37,504
    const size_t offs_off     = (base_off + base_bytes + 15) & ~(size_t)15;
    const size_t offs_bytes   = (size_t)(N_NODES + 1) * sizeof(int);         // 600,004
    const size_t binned_off   = (offs_off + offs_bytes + 15) & ~(size_t)15;
    const size_t edges2_off   = (binned_off + edges_bytes + 15) & ~(size_t)15;
    const size_t need_sort    = edges2_off + edges_bytes;                    // ~206 MB

    // ---- Tier-2 workspace layout: previous round (single random scatter) ----
    const size_t t2_off_bytes    = (size_t)(N_NODES + 1) * sizeof(int);
    const size_t t2_cursor_off   = (t2_off_bytes + 15) & ~(size_t)15;
    const size_t t2_cursor_bytes = (size_t)N_NODES * sizeof(int);
    const size_t t2_edges_off    = (t2_cursor_off + t2_cursor_bytes + 15) & ~(size_t)15;
    const size_t need_old        = t2_edges_off + edges_bytes;               // ~104 MB

    const int eb = (N_NNZ + 255) / 256;
    const int gb = (N_NODES * 64 + 255) / 256;

    if (ws_size >= need_sort) {
        int*  padded  = (int*)d_ws;
        int*  base    = (int*)((char*)d_ws + base_off);
        int*  offsets = (int*)((char*)d_ws + offs_off);
        int2* binned  = (int2*)((char*)d_ws + binned_off);
        int2* edges   = (int2*)((char*)d_ws + edges2_off);

        hipMemsetAsync(padded, 0, padded_bytes, stream);
        bucket_hist_kernel<<<eb, 256, 0, stream>>>(rows, cols, padded);
        bucket_scan_kernel<<<1, 1024, 0, stream>>>(padded, base);
        bin_kernel<<<eb, 256, 0, stream>>>(rows, cols, vals, padded, binned);
        bucket_scatter_kernel<<<NBUCKETS, 256, 0, stream>>>(base, binned, offsets, edges);

        for (int l = 1; l <= N_LAYER; ++l) {
            const float* lat_prev = lats + (size_t)(l - 1) * N;
            gather_kernel<<<gb, 256, 0, stream>>>(
                offsets, edges, lat_prev,
                gcn  + (size_t)l * N,
                lats + (size_t)l * N);
        }
    } else if (ws_size >= need_old) {
        int*  offsets = (int*)d_ws;
        int*  cursor  = (int*)((char*)d_ws + t2_cursor_off);
        int2* edges   = (int2*)((char*)d_ws + t2_edges_off);

        hipMemsetAsync(offsets, 0, t2_off_bytes, stream);
        histogram_kernel<<<eb, 256, 0, stream>>>(rows, cols, offsets);
        scan_kernel<<<1, 1024, 0, stream>>>(offsets, N_NODES + 1);
        hipMemcpyAsync(cursor, offsets, t2_cursor_bytes, hipMemcpyDeviceToDevice, stream);
        fill_kernel<<<eb, 256, 0, stream>>>(rows, cols, vals, cursor, edges);

        for (int l = 1; l <= N_LAYER; ++l) {
            const float* lat_prev = lats + (size_t)(l - 1) * N;
            gather_kernel<<<gb, 256, 0, stream>>>(
                offsets, edges, lat_prev,
                gcn  + (size_t)l * N,
                lats + (size_t)l * N);
        }
    } else {
        hipMemsetAsync(gcn + N, 0, 3 * N * sizeof(float), stream);
        const int scatter_blocks = (N_NNZ * 64 + 255) / 256;
        const int n4 = (int)(N / 4);
        const int add_blocks = (n4 + 255) / 256;
        for (int l = 1; l <= N_LAYER; ++l) {
            const float* lat_prev = lats + (size_t)(l - 1) * N;
            float* gcn_l = gcn  + (size_t)l * N;
            float* lat_l = lats + (size_t)l * N;
            scatter_kernel<<<scatter_blocks, 256, 0, stream>>>(
                rows, cols, vals, lat_prev, gcn_l);
            residual_add_kernel<<<add_blocks, 256, 0, stream>>>(
                (const float4*)lat_prev, (const float4*)gcn_l, (float4*)lat_l, n4);
        }
    }
}

// Round 2
// 2001.137 us; speedup vs baseline: 1.6330x; 1.5471x over previous
//
#include <hip/hip_runtime.h>

#define N_USER 100000
#define N_ITEM 50000
#define N_NODES 150000
#define DIM 64
#define N_NNZ 6400000
#define N_LAYER 3
#define TOTAL_EDGES (2 * N_NNZ)   // each nnz contributes to one user row and one item row

// ---------------------------------------------------------------------------
// Segmented counting sort: super-bucket = 256 consecutive nodes.
// Positions are pre-partitioned per (block, super-bucket) via count+scan, so
// the scatter needs NO global atomics and each (blk,sb) run (~680B) is written
// entirely by one block on one CU -> full line merging in that XCD's L2.
// ---------------------------------------------------------------------------
#define SB_SHIFT 8
#define NODES_PER_SB 256
#define NSB ((N_NODES + NODES_PER_SB - 1) / NODES_PER_SB)   // 586
#define NB 256                    // number of binning blocks
#define EPB (N_NNZ / NB)          // 25000 edges per block (divides exactly)
#define BIN_THREADS 1024

// Phase A1: per-block histogram over super-buckets.
__global__ __launch_bounds__(BIN_THREADS) void count_kernel(
    const int* __restrict__ rows,
    const int* __restrict__ cols,
    int* __restrict__ counts)     // [NSB*NB + 1], counts[sb*NB + blk]
{
    __shared__ int cnt[NSB];
    for (int i = threadIdx.x; i < NSB; i += BIN_THREADS) cnt[i] = 0;
    __syncthreads();

    const int e0 = blockIdx.x * EPB;
    for (int e = e0 + (int)threadIdx.x; e < e0 + EPB; e += BIN_THREADS) {
        const int r = rows[e];
        const int c = N_USER + cols[e];
        atomicAdd(&cnt[r >> SB_SHIFT], 1);
        atomicAdd(&cnt[c >> SB_SHIFT], 1);
    }
    __syncthreads();

    for (int i = threadIdx.x; i < NSB; i += BIN_THREADS)
        counts[i * NB + blockIdx.x] = cnt[i];
    if (blockIdx.x == 0 && threadIdx.x == 0) counts[NSB * NB] = 0;  // scan sentinel
}

// Exclusive scan in place, single block (n up to ~150K; ~147 chunks).
__global__ __launch_bounds__(1024) void scan_kernel(int* __restrict__ data, int n)
{
    __shared__ int wsum[16];
    __shared__ int woff[16];
    __shared__ int carry_s;
    if (threadIdx.x == 0) carry_s = 0;
    __syncthreads();

    const int lane = threadIdx.x & 63;
    const int wid  = threadIdx.x >> 6;

    for (int base = 0; base < n; base += 1024) {
        int i = base + (int)threadIdx.x;
        int v = (i < n) ? data[i] : 0;

        int incl = v;
        #pragma unroll
        for (int off = 1; off < 64; off <<= 1) {
            int t = __shfl_up(incl, off, 64);
            if (lane >= off) incl += t;
        }
        if (lane == 63) wsum[wid] = incl;
        __syncthreads();

        if (threadIdx.x == 0) {
            int s = carry_s;
            #pragma unroll
            for (int w = 0; w < 16; ++w) { woff[w] = s; s += wsum[w]; }
            carry_s = s;
        }
        __syncthreads();

        if (i < n) data[i] = woff[wid] + incl - v;   // exclusive
        __syncthreads();
    }
}

// Phase A3: deterministic scatter into super-bucket-grouped order.
// Record: x = (node_low8 << 18) | src   (src < 150000 < 2^18), y = val bits.
__global__ __launch_bounds__(BIN_THREADS) void bin2_kernel(
    const int* __restrict__ rows,
    const int* __restrict__ cols,
    const float* __restrict__ vals,
    const int* __restrict__ base,   // scanned counts: base[sb*NB + blk]
    int2* __restrict__ binned)      // [TOTAL_EDGES]
{
    __shared__ int cur[NSB];
    for (int i = threadIdx.x; i < NSB; i += BIN_THREADS)
        cur[i] = base[i * NB + blockIdx.x];
    __syncthreads();

    const int e0 = blockIdx.x * EPB;
    for (int e = e0 + (int)threadIdx.x; e < e0 + EPB; e += BIN_THREADS) {
        const int r  = rows[e];
        const int c  = N_USER + cols[e];
        const int vb = __float_as_int(vals[e]);
        // user row r gathers from item node c
        int p1 = atomicAdd(&cur[r >> SB_SHIFT], 1);
        binned[p1] = make_int2(((r & (NODES_PER_SB - 1)) << 18) | c, vb);
        // item row c gathers from user node r
        int p2 = atomicAdd(&cur[c >> SB_SHIFT], 1);
        binned[p2] = make_int2(((c & (NODES_PER_SB - 1)) << 18) | r, vb);
    }
}

// Phase B: per-super-bucket local sort to node granularity (one block per sb,
// ~44K records in a ~350KB window -> L2-resident on its XCD). Also writes the
// per-node CSR offsets.
__global__ __launch_bounds__(1024) void fine_scatter_kernel(
    const int* __restrict__ base,    // [NSB*NB + 1] scanned
    const int2* __restrict__ binned,
    int* __restrict__ offsets,       // [N_NODES + 1]
    int2* __restrict__ edges)        // [TOTAL_EDGES] final (src, val)
{
    const int b   = blockIdx.x;
    const int tid = threadIdx.x;
    const int s0  = base[b * NB];
    const int s1  = base[(b + 1) * NB];   // sentinel makes this valid for last b

    __shared__ int cnt[NODES_PER_SB];
    __shared__ int ofs[NODES_PER_SB];
    if (tid < NODES_PER_SB) cnt[tid] = 0;
    __syncthreads();

    for (int i = s0 + tid; i < s1; i += 1024)
        atomicAdd(&cnt[binned[i].x >> 18], 1);
    __syncthreads();

    if (tid == 0) {
        int s = 0;
        #pragma unroll 8
        for (int j = 0; j < NODES_PER_SB; ++j) { ofs[j] = s; s += cnt[j]; }
    }
    __syncthreads();

    if (tid < NODES_PER_SB) {
        const int node = b * NODES_PER_SB + tid;
        if (node < N_NODES) offsets[node] = s0 + ofs[tid];
        cnt[tid] = ofs[tid];    // becomes intra-window cursor
    }
    if (b == (int)gridDim.x - 1 && tid == 0) offsets[N_NODES] = TOTAL_EDGES;
    __syncthreads();

    // second read hits L2 (this block just fetched the window)
    for (int i = s0 + tid; i < s1; i += 1024) {
        int2 rec = binned[i];
        int nl   = rec.x >> 18;
        int src  = rec.x & 0x3FFFF;
        int p    = s0 + atomicAdd(&cnt[nl], 1);
        edges[p] = make_int2(src, rec.y);
    }
}

// ---------------------------------------------------------------------------
// Gather propagation: one wave per output row, lane = dim. Fused residual.
// ---------------------------------------------------------------------------
__global__ __launch_bounds__(256) void gather_kernel(
    const int* __restrict__ offsets,
    const int2* __restrict__ edges,
    const float* __restrict__ lat_prev,
    float* __restrict__ gcn_l,
    float* __restrict__ lat_l)
{
    const int gtid = blockIdx.x * blockDim.x + threadIdx.x;
    const int node = gtid >> 6;
    const int lane = gtid & 63;
    if (node >= N_NODES) return;

    const int beg = offsets[node];
    const int end = offsets[node + 1];

    float acc = 0.f;
    int e = beg;
    for (; e + 4 <= end; e += 4) {
        int2 e0 = edges[e];
        int2 e1 = edges[e + 1];
        int2 e2 = edges[e + 2];
        int2 e3 = edges[e + 3];
        float x0 = lat_prev[(size_t)e0.x * DIM + lane];
        float x1 = lat_prev[(size_t)e1.x * DIM + lane];
        float x2 = lat_prev[(size_t)e2.x * DIM + lane];
        float x3 = lat_prev[(size_t)e3.x * DIM + lane];
        acc += __int_as_float(e0.y) * x0;
        acc += __int_as_float(e1.y) * x1;
        acc += __int_as_float(e2.y) * x2;
        acc += __int_as_float(e3.y) * x3;
    }
    for (; e < end; ++e) {
        int2 ee = edges[e];
        acc += __int_as_float(ee.y) * lat_prev[(size_t)ee.x * DIM + lane];
    }

    const size_t o = (size_t)node * DIM + lane;
    gcn_l[o] = acc;
    lat_l[o] = lat_prev[o] + acc;
}

// ---------------------------------------------------------------------------
// Fallback tier 2: single-pass CSR build (global random scatter fill)
// ---------------------------------------------------------------------------
__global__ __launch_bounds__(256) void histogram_kernel(
    const int* __restrict__ rows,
    const int* __restrict__ cols,
    int* __restrict__ counts)
{
    int e = blockIdx.x * blockDim.x + threadIdx.x;
    if (e >= N_NNZ) return;
    atomicAdd(&counts[rows[e]], 1);
    atomicAdd(&counts[N_USER + cols[e]], 1);
}

__global__ __launch_bounds__(256) void fill_kernel(
    const int* __restrict__ rows,
    const int* __restrict__ cols,
    const float* __restrict__ vals,
    int* __restrict__ cursor,
    int2* __restrict__ edges)
{
    int e = blockIdx.x * blockDim.x + threadIdx.x;
    if (e >= N_NNZ) return;
    const int r = rows[e];
    const int c = cols[e];
    const int vb = __float_as_int(vals[e]);
    int pu = atomicAdd(&cursor[r], 1);
    edges[pu] = make_int2(N_USER + c, vb);
    int pi = atomicAdd(&cursor[N_USER + c], 1);
    edges[pi] = make_int2(r, vb);
}

// ---------------------------------------------------------------------------
// Fallback tier 3: atomic scatter
// ---------------------------------------------------------------------------
__global__ __launch_bounds__(256) void scatter_kernel(
    const int* __restrict__ rows,
    const int* __restrict__ cols,
    const float* __restrict__ vals,
    const float* __restrict__ lat_prev,
    float* __restrict__ gcn_out)
{
    const int gtid = blockIdx.x * blockDim.x + threadIdx.x;
    const int edge = gtid >> 6;
    const int lane = gtid & 63;
    if (edge >= N_NNZ) return;
    const int r = rows[edge];
    const int c = cols[edge];
    const float v = vals[edge];
    atomicAdd(&gcn_out[(size_t)r * DIM + lane],
              v * lat_prev[(size_t)(N_USER + c) * DIM + lane]);
    atomicAdd(&gcn_out[(size_t)(N_USER + c) * DIM + lane],
              v * lat_prev[(size_t)r * DIM + lane]);
}

__global__ __launch_bounds__(256) void residual_add_kernel(
    const float4* __restrict__ a,
    const float4* __restrict__ b,
    float4* __restrict__ out,
    int n4)
{
    int i = blockIdx.x * blockDim.x + threadIdx.x;
    if (i < n4) {
        float4 av = a[i], bv = b[i];
        out[i] = make_float4(av.x + bv.x, av.y + bv.y, av.z + bv.z, av.w + bv.w);
    }
}

extern "C" void kernel_launch(void* const* d_in, const int* in_sizes, int n_in,
                              void* d_out, int out_size, void* d_ws, size_t ws_size,
                              hipStream_t stream) {
    const int*   rows   = (const int*)d_in[0];
    const int*   cols   = (const int*)d_in[1];
    const float* vals   = (const float*)d_in[2];
    const float* embeds = (const float*)d_in[3];

    float* out = (float*)d_out;
    const size_t N = (size_t)N_NODES * DIM;   // floats per snapshot

    float* lats = out;            // [4][N_NODES][DIM]
    float* gcn  = out + 4 * N;    // [4][N_NODES][DIM]

    // lats[0] = gcn[0] = embeds
    hipMemcpyAsync(lats, embeds, N * sizeof(float), hipMemcpyDeviceToDevice, stream);
    hipMemcpyAsync(gcn,  embeds, N * sizeof(float), hipMemcpyDeviceToDevice, stream);

    const size_t edges_bytes = (size_t)TOTAL_EDGES * sizeof(int2);   // 102,400,000

    // ---- Tier-1 workspace layout: segmented counting sort ----
    const size_t mat_bytes   = (size_t)(NSB * NB + 1) * sizeof(int);         // 600,068
    const size_t offs_off    = (mat_bytes + 15) & ~(size_t)15;
    const size_t offs_bytes  = (size_t)(N_NODES + 1) * sizeof(int);          // 600,004
    const size_t binned_off  = (offs_off + offs_bytes + 15) & ~(size_t)15;
    const size_t edges2_off  = (binned_off + edges_bytes + 15) & ~(size_t)15;
    const size_t need_sort   = edges2_off + edges_bytes;                     // ~206 MB

    // ---- Tier-2 workspace layout ----
    const size_t t2_off_bytes    = (size_t)(N_NODES + 1) * sizeof(int);
    const size_t t2_cursor_off   = (t2_off_bytes + 15) & ~(size_t)15;
    const size_t t2_cursor_bytes = (size_t)N_NODES * sizeof(int);
    const size_t t2_edges_off    = (t2_cursor_off + t2_cursor_bytes + 15) & ~(size_t)15;
    const size_t need_old        = t2_edges_off + edges_bytes;               // ~104 MB

    const int eb = (N_NNZ + 255) / 256;
    const int gb = (N_NODES * 64 + 255) / 256;

    if (ws_size >= need_sort) {
        int*  mat     = (int*)d_ws;                       // counts -> scanned bases
        int*  offsets = (int*)((char*)d_ws + offs_off);
        int2* binned  = (int2*)((char*)d_ws + binned_off);
        int2* edges   = (int2*)((char*)d_ws + edges2_off);

        count_kernel<<<NB, BIN_THREADS, 0, stream>>>(rows, cols, mat);
        scan_kernel<<<1, 1024, 0, stream>>>(mat, NSB * NB + 1);
        bin2_kernel<<<NB, BIN_THREADS, 0, stream>>>(rows, cols, vals, mat, binned);
        fine_scatter_kernel<<<NSB, 1024, 0, stream>>>(mat, binned, offsets, edges);

        for (int l = 1; l <= N_LAYER; ++l) {
            const float* lat_prev = lats + (size_t)(l - 1) * N;
            gather_kernel<<<gb, 256, 0, stream>>>(
                offsets, edges, lat_prev,
                gcn  + (size_t)l * N,
                lats + (size_t)l * N);
        }
    } else if (ws_size >= need_old) {
        int*  offsets = (int*)d_ws;
        int*  cursor  = (int*)((char*)d_ws + t2_cursor_off);
        int2* edges   = (int2*)((char*)d_ws + t2_edges_off);

        hipMemsetAsync(offsets, 0, t2_off_bytes, stream);
        histogram_kernel<<<eb, 256, 0, stream>>>(rows, cols, offsets);
        scan_kernel<<<1, 1024, 0, stream>>>(offsets, N_NODES + 1);
        hipMemcpyAsync(cursor, offsets, t2_cursor_bytes, hipMemcpyDeviceToDevice, stream);
        fill_kernel<<<eb, 256, 0, stream>>>(rows, cols, vals, cursor, edges);

        for (int l = 1; l <= N_LAYER; ++l) {
            const float* lat_prev = lats + (size_t)(l - 1) * N;
            gather_kernel<<<gb, 256, 0, stream>>>(
                offsets, edges, lat_prev,
                gcn  + (size_t)l * N,
                lats + (size_t)l * N);
        }
    } else {
        hipMemsetAsync(gcn + N, 0, 3 * N * sizeof(float), stream);
        const int scatter_blocks = (N_NNZ * 64 + 255) / 256;
        const int n4 = (int)(N / 4);
        const int add_blocks = (n4 + 255) / 256;
        for (int l = 1; l <= N_LAYER; ++l) {
            const float* lat_prev = lats + (size_t)(l - 1) * N;
            float* gcn_l = gcn  + (size_t)l * N;
            float* lat_l = lats + (size_t)l * N;
            scatter_kernel<<<scatter_blocks, 256, 0, stream>>>(
                rows, cols, vals, lat_prev, gcn_l);
            residual_add_kernel<<<add_blocks, 256, 0, stream>>>(
                (const float4*)lat_prev, (const float4*)gcn_l, (float4*)lat_l, n4);
        }
    }
}

// Round 3
// 1848.042 us; speedup vs baseline: 1.7683x; 1.0828x over previous
//
#include <hip/hip_runtime.h>

#define N_USER 100000
#define N_ITEM 50000
#define N_NODES 150000
#define DIM 64
#define N_NNZ 6400000
#define N_LAYER 3
#define TOTAL_EDGES (2 * N_NNZ)   // each nnz contributes to one user row and one item row

// ---------------------------------------------------------------------------
// Segmented counting sort: super-bucket = 256 consecutive nodes.
// Positions are pre-partitioned per (block, super-bucket) via count+scan, so
// the scatter needs NO global atomics and each (blk,sb) run (~680B) is written
// entirely by one block on one CU -> full line merging in that XCD's L2.
// ---------------------------------------------------------------------------
#define SB_SHIFT 8
#define NODES_PER_SB 256
#define NSB ((N_NODES + NODES_PER_SB - 1) / NODES_PER_SB)   // 586
#define NB 256                    // number of binning blocks
#define EPB (N_NNZ / NB)          // 25000 edges per block (divides exactly)
#define BIN_THREADS 1024

// Phase A1: per-block histogram over super-buckets.
__global__ __launch_bounds__(BIN_THREADS) void count_kernel(
    const int* __restrict__ rows,
    const int* __restrict__ cols,
    int* __restrict__ counts)     // [NSB*NB + 1], counts[sb*NB + blk]
{
    __shared__ int cnt[NSB];
    for (int i = threadIdx.x; i < NSB; i += BIN_THREADS) cnt[i] = 0;
    __syncthreads();

    const int e0 = blockIdx.x * EPB;
    for (int e = e0 + (int)threadIdx.x; e < e0 + EPB; e += BIN_THREADS) {
        const int r = rows[e];
        const int c = N_USER + cols[e];
        atomicAdd(&cnt[r >> SB_SHIFT], 1);
        atomicAdd(&cnt[c >> SB_SHIFT], 1);
    }
    __syncthreads();

    for (int i = threadIdx.x; i < NSB; i += BIN_THREADS)
        counts[i * NB + blockIdx.x] = cnt[i];
    if (blockIdx.x == 0 && threadIdx.x == 0) counts[NSB * NB] = 0;  // scan sentinel
}

// Exclusive scan in place, single block (n up to ~150K; ~147 chunks).
__global__ __launch_bounds__(1024) void scan_kernel(int* __restrict__ data, int n)
{
    __shared__ int wsum[16];
    __shared__ int woff[16];
    __shared__ int carry_s;
    if (threadIdx.x == 0) carry_s = 0;
    __syncthreads();

    const int lane = threadIdx.x & 63;
    const int wid  = threadIdx.x >> 6;

    for (int base = 0; base < n; base += 1024) {
        int i = base + (int)threadIdx.x;
        int v = (i < n) ? data[i] : 0;

        int incl = v;
        #pragma unroll
        for (int off = 1; off < 64; off <<= 1) {
            int t = __shfl_up(incl, off, 64);
            if (lane >= off) incl += t;
        }
        if (lane == 63) wsum[wid] = incl;
        __syncthreads();

        if (threadIdx.x == 0) {
            int s = carry_s;
            #pragma unroll
            for (int w = 0; w < 16; ++w) { woff[w] = s; s += wsum[w]; }
            carry_s = s;
        }
        __syncthreads();

        if (i < n) data[i] = woff[wid] + incl - v;   // exclusive
        __syncthreads();
    }
}

// Phase A3: deterministic scatter into super-bucket-grouped order.
// Record: x = (node_low8 << 18) | src   (src < 150000 < 2^18), y = val bits.
__global__ __launch_bounds__(BIN_THREADS) void bin2_kernel(
    const int* __restrict__ rows,
    const int* __restrict__ cols,
    const float* __restrict__ vals,
    const int* __restrict__ base,   // scanned counts: base[sb*NB + blk]
    int2* __restrict__ binned)      // [TOTAL_EDGES]
{
    __shared__ int cur[NSB];
    for (int i = threadIdx.x; i < NSB; i += BIN_THREADS)
        cur[i] = base[i * NB + blockIdx.x];
    __syncthreads();

    const int e0 = blockIdx.x * EPB;
    for (int e = e0 + (int)threadIdx.x; e < e0 + EPB; e += BIN_THREADS) {
        const int r  = rows[e];
        const int c  = N_USER + cols[e];
        const int vb = __float_as_int(vals[e]);
        // user row r gathers from item node c
        int p1 = atomicAdd(&cur[r >> SB_SHIFT], 1);
        binned[p1] = make_int2(((r & (NODES_PER_SB - 1)) << 18) | c, vb);
        // item row c gathers from user node r
        int p2 = atomicAdd(&cur[c >> SB_SHIFT], 1);
        binned[p2] = make_int2(((c & (NODES_PER_SB - 1)) << 18) | r, vb);
    }
}

// Phase B: per-super-bucket local sort to node granularity (one block per sb,
// ~44K records in a ~350KB window -> L2-resident on its XCD). Also writes the
// per-node CSR offsets.
__global__ __launch_bounds__(1024) void fine_scatter_kernel(
    const int* __restrict__ base,    // [NSB*NB + 1] scanned
    const int2* __restrict__ binned,
    int* __restrict__ offsets,       // [N_NODES + 1]
    int2* __restrict__ edges)        // [TOTAL_EDGES] final (src, val)
{
    const int b   = blockIdx.x;
    const int tid = threadIdx.x;
    const int s0  = base[b * NB];
    const int s1  = base[(b + 1) * NB];   // sentinel makes this valid for last b

    __shared__ int cnt[NODES_PER_SB];
    __shared__ int ofs[NODES_PER_SB];
    if (tid < NODES_PER_SB) cnt[tid] = 0;
    __syncthreads();

    for (int i = s0 + tid; i < s1; i += 1024)
        atomicAdd(&cnt[binned[i].x >> 18], 1);
    __syncthreads();

    if (tid == 0) {
        int s = 0;
        #pragma unroll 8
        for (int j = 0; j < NODES_PER_SB; ++j) { ofs[j] = s; s += cnt[j]; }
    }
    __syncthreads();

    if (tid < NODES_PER_SB) {
        const int node = b * NODES_PER_SB + tid;
        if (node < N_NODES) offsets[node] = s0 + ofs[tid];
        cnt[tid] = ofs[tid];    // becomes intra-window cursor
    }
    if (b == (int)gridDim.x - 1 && tid == 0) offsets[N_NODES] = TOTAL_EDGES;
    __syncthreads();

    // second read hits L2 (this block just fetched the window)
    for (int i = s0 + tid; i < s1; i += 1024) {
        int2 rec = binned[i];
        int nl   = rec.x >> 18;
        int src  = rec.x & 0x3FFFF;
        int p    = s0 + atomicAdd(&cnt[nl], 1);
        edges[p] = make_int2(src, rec.y);
    }
}

// ---------------------------------------------------------------------------
// Gather propagation: one wave per output row, lane = dim. Fused residual.
// Edge tile (64 edges) loaded coalesced, broadcast via shfl; 8 independent
// row-gathers in flight per step. Non-temporal on streams to protect L2.
// ---------------------------------------------------------------------------
__global__ __launch_bounds__(256) void gather_kernel(
    const int* __restrict__ offsets,
    const int2* __restrict__ edges,
    const float* __restrict__ lat_prev,
    float* __restrict__ gcn_l,
    float* __restrict__ lat_l)
{
    const int gtid = blockIdx.x * blockDim.x + threadIdx.x;
    const int node = gtid >> 6;
    const int lane = gtid & 63;
    if (node >= N_NODES) return;

    const int beg = offsets[node];
    const int end = offsets[node + 1];
    const long long* ep = reinterpret_cast<const long long*>(edges);

    float acc = 0.f;
    for (int t = beg; t < end; t += 64) {
        const int idx = t + lane;
        // coalesced 512B edge-tile load; streamed, keep out of L2's hot set
        long long my = (idx < end) ? __builtin_nontemporal_load(ep + idx) : 0LL;
        const int m = min(64, end - t);
        int k = 0;
        for (; k + 8 <= m; k += 8) {
            long long p0 = __shfl(my, k + 0);
            long long p1 = __shfl(my, k + 1);
            long long p2 = __shfl(my, k + 2);
            long long p3 = __shfl(my, k + 3);
            long long p4 = __shfl(my, k + 4);
            long long p5 = __shfl(my, k + 5);
            long long p6 = __shfl(my, k + 6);
            long long p7 = __shfl(my, k + 7);
            float x0 = lat_prev[(((int)p0) << 6) | lane];
            float x1 = lat_prev[(((int)p1) << 6) | lane];
            float x2 = lat_prev[(((int)p2) << 6) | lane];
            float x3 = lat_prev[(((int)p3) << 6) | lane];
            float x4 = lat_prev[(((int)p4) << 6) | lane];
            float x5 = lat_prev[(((int)p5) << 6) | lane];
            float x6 = lat_prev[(((int)p6) << 6) | lane];
            float x7 = lat_prev[(((int)p7) << 6) | lane];
            acc += __int_as_float((int)(p0 >> 32)) * x0;
            acc += __int_as_float((int)(p1 >> 32)) * x1;
            acc += __int_as_float((int)(p2 >> 32)) * x2;
            acc += __int_as_float((int)(p3 >> 32)) * x3;
            acc += __int_as_float((int)(p4 >> 32)) * x4;
            acc += __int_as_float((int)(p5 >> 32)) * x5;
            acc += __int_as_float((int)(p6 >> 32)) * x6;
            acc += __int_as_float((int)(p7 >> 32)) * x7;
        }
        for (; k < m; ++k) {
            long long p = __shfl(my, k);
            acc += __int_as_float((int)(p >> 32)) * lat_prev[(((int)p) << 6) | lane];
        }
    }

    // o = node*64 + lane == gtid
    const int o = gtid;
    __builtin_nontemporal_store(acc, &gcn_l[o]);
    __builtin_nontemporal_store(lat_prev[o] + acc, &lat_l[o]);
}

// ---------------------------------------------------------------------------
// Fallback tier 2: single-pass CSR build (global random scatter fill)
// ---------------------------------------------------------------------------
__global__ __launch_bounds__(256) void histogram_kernel(
    const int* __restrict__ rows,
    const int* __restrict__ cols,
    int* __restrict__ counts)
{
    int e = blockIdx.x * blockDim.x + threadIdx.x;
    if (e >= N_NNZ) return;
    atomicAdd(&counts[rows[e]], 1);
    atomicAdd(&counts[N_USER + cols[e]], 1);
}

__global__ __launch_bounds__(256) void fill_kernel(
    const int* __restrict__ rows,
    const int* __restrict__ cols,
    const float* __restrict__ vals,
    int* __restrict__ cursor,
    int2* __restrict__ edges)
{
    int e = blockIdx.x * blockDim.x + threadIdx.x;
    if (e >= N_NNZ) return;
    const int r = rows[e];
    const int c = cols[e];
    const int vb = __float_as_int(vals[e]);
    int pu = atomicAdd(&cursor[r], 1);
    edges[pu] = make_int2(N_USER + c, vb);
    int pi = atomicAdd(&cursor[N_USER + c], 1);
    edges[pi] = make_int2(r, vb);
}

// ---------------------------------------------------------------------------
// Fallback tier 3: atomic scatter
// ---------------------------------------------------------------------------
__global__ __launch_bounds__(256) void scatter_kernel(
    const int* __restrict__ rows,
    const int* __restrict__ cols,
    const float* __restrict__ vals,
    const float* __restrict__ lat_prev,
    float* __restrict__ gcn_out)
{
    const int gtid = blockIdx.x * blockDim.x + threadIdx.x;
    const int edge = gtid >> 6;
    const int lane = gtid & 63;
    if (edge >= N_NNZ) return;
    const int r = rows[edge];
    const int c = cols[edge];
    const float v = vals[edge];
    atomicAdd(&gcn_out[(size_t)r * DIM + lane],
              v * lat_prev[(size_t)(N_USER + c) * DIM + lane]);
    atomicAdd(&gcn_out[(size_t)(N_USER + c) * DIM + lane],
              v * lat_prev[(size_t)r * DIM + lane]);
}

__global__ __launch_bounds__(256) void residual_add_kernel(
    const float4* __restrict__ a,
    const float4* __restrict__ b,
    float4* __restrict__ out,
    int n4)
{
    int i = blockIdx.x * blockDim.x + threadIdx.x;
    if (i < n4) {
        float4 av = a[i], bv = b[i];
        out[i] = make_float4(av.x + bv.x, av.y + bv.y, av.z + bv.z, av.w + bv.w);
    }
}

extern "C" void kernel_launch(void* const* d_in, const int* in_sizes, int n_in,
                              void* d_out, int out_size, void* d_ws, size_t ws_size,
                              hipStream_t stream) {
    const int*   rows   = (const int*)d_in[0];
    const int*   cols   = (const int*)d_in[1];
    const float* vals   = (const float*)d_in[2];
    const float* embeds = (const float*)d_in[3];

    float* out = (float*)d_out;
    const size_t N = (size_t)N_NODES * DIM;   // floats per snapshot

    float* lats = out;            // [4][N_NODES][DIM]
    float* gcn  = out + 4 * N;    // [4][N_NODES][DIM]

    // lats[0] = gcn[0] = embeds
    hipMemcpyAsync(lats, embeds, N * sizeof(float), hipMemcpyDeviceToDevice, stream);
    hipMemcpyAsync(gcn,  embeds, N * sizeof(float), hipMemcpyDeviceToDevice, stream);

    const size_t edges_bytes = (size_t)TOTAL_EDGES * sizeof(int2);   // 102,400,000

    // ---- Tier-1 workspace layout: segmented counting sort ----
    const size_t mat_bytes   = (size_t)(NSB * NB + 1) * sizeof(int);         // 600,068
    const size_t offs_off    = (mat_bytes + 15) & ~(size_t)15;
    const size_t offs_bytes  = (size_t)(N_NODES + 1) * sizeof(int);          // 600,004
    const size_t binned_off  = (offs_off + offs_bytes + 15) & ~(size_t)15;
    const size_t edges2_off  = (binned_off + edges_bytes + 15) & ~(size_t)15;
    const size_t need_sort   = edges2_off + edges_bytes;                     // ~206 MB

    // ---- Tier-2 workspace layout ----
    const size_t t2_off_bytes    = (size_t)(N_NODES + 1) * sizeof(int);
    const size_t t2_cursor_off   = (t2_off_bytes + 15) & ~(size_t)15;
    const size_t t2_cursor_bytes = (size_t)N_NODES * sizeof(int);
    const size_t t2_edges_off    = (t2_cursor_off + t2_cursor_bytes + 15) & ~(size_t)15;
    const size_t need_old        = t2_edges_off + edges_bytes;               // ~104 MB

    const int eb = (N_NNZ + 255) / 256;
    const int gb = (N_NODES * 64 + 255) / 256;

    if (ws_size >= need_sort) {
        int*  mat     = (int*)d_ws;                       // counts -> scanned bases
        int*  offsets = (int*)((char*)d_ws + offs_off);
        int2* binned  = (int2*)((char*)d_ws + binned_off);
        int2* edges   = (int2*)((char*)d_ws + edges2_off);

        count_kernel<<<NB, BIN_THREADS, 0, stream>>>(rows, cols, mat);
        scan_kernel<<<1, 1024, 0, stream>>>(mat, NSB * NB + 1);
        bin2_kernel<<<NB, BIN_THREADS, 0, stream>>>(rows, cols, vals, mat, binned);
        fine_scatter_kernel<<<NSB, 1024, 0, stream>>>(mat, binned, offsets, edges);

        for (int l = 1; l <= N_LAYER; ++l) {
            const float* lat_prev = lats + (size_t)(l - 1) * N;
            gather_kernel<<<gb, 256, 0, stream>>>(
                offsets, edges, lat_prev,
                gcn  + (size_t)l * N,
                lats + (size_t)l * N);
        }
    } else if (ws_size >= need_old) {
        int*  offsets = (int*)d_ws;
        int*  cursor  = (int*)((char*)d_ws + t2_cursor_off);
        int2* edges   = (int2*)((char*)d_ws + t2_edges_off);

        hipMemsetAsync(offsets, 0, t2_off_bytes, stream);
        histogram_kernel<<<eb, 256, 0, stream>>>(rows, cols, offsets);
        scan_kernel<<<1, 1024, 0, stream>>>(offsets, N_NODES + 1);
        hipMemcpyAsync(cursor, offsets, t2_cursor_bytes, hipMemcpyDeviceToDevice, stream);
        fill_kernel<<<eb, 256, 0, stream>>>(rows, cols, vals, cursor, edges);

        for (int l = 1; l <= N_LAYER; ++l) {
            const float* lat_prev = lats + (size_t)(l - 1) * N;
            gather_kernel<<<gb, 256, 0, stream>>>(
                offsets, edges, lat_prev,
                gcn  + (size_t)l * N,
                lats + (size_t)l * N);
        }
    } else {
        hipMemsetAsync(gcn + N, 0, 3 * N * sizeof(float), stream);
        const int scatter_blocks = (N_NNZ * 64 + 255) / 256;
        const int n4 = (int)(N / 4);
        const int add_blocks = (n4 + 255) / 256;
        for (int l = 1; l <= N_LAYER; ++l) {
            const float* lat_prev = lats + (size_t)(l - 1) * N;
            float* gcn_l = gcn  + (size_t)l * N;
            float* lat_l = lats + (size_t)l * N;
            scatter_kernel<<<scatter_blocks, 256, 0, stream>>>(
                rows, cols, vals, lat_prev, gcn_l);
            residual_add_kernel<<<add_blocks, 256, 0, stream>>>(
                (const float4*)lat_prev, (const float4*)gcn_l, (float4*)lat_l, n4);
        }
    }
}

// Round 4
// 1769.844 us; speedup vs baseline: 1.8464x; 1.0442x over previous
//
#include <hip/hip_runtime.h>

#define N_USER 100000
#define N_ITEM 50000
#define N_NODES 150000
#define DIM 64
#define N_NNZ 6400000
#define N_LAYER 3
#define TOTAL_EDGES (2 * N_NNZ)   // each nnz contributes to one user row and one item row

// ---------------------------------------------------------------------------
// Segmented counting sort: super-bucket = 256 consecutive nodes.
// Positions are pre-partitioned per (block, super-bucket) via count+scan, so
// the scatter needs NO global atomics and each (blk,sb) run (~680B) is written
// entirely by one block on one CU -> full line merging in that XCD's L2.
// ---------------------------------------------------------------------------
#define SB_SHIFT 8
#define NODES_PER_SB 256
#define NSB ((N_NODES + NODES_PER_SB - 1) / NODES_PER_SB)   // 586
#define NB 256                    // number of binning blocks
#define EPB (N_NNZ / NB)          // 25000 edges per block (divides exactly)
#define BIN_THREADS 1024

// Secondary sort key inside fine_scatter: source-row bucket (~16K rows = 4MB
// of embedding table, ~ one XCD's L2). Banding: all waves traverse their edge
// lists in src-bucket order -> concurrent gathers cluster in a small table band.
#define SRC_BK_SHIFT 14
#define NBK 10                                   // ceil(150000 / 16384)
#define NKEY (NODES_PER_SB * NBK)                // 2560

// Hierarchical scan over the counts matrix
#define SCAN_N (NSB * NB + 1)                    // 150017
#define SCAN_TILE 4096
#define NSCAN ((SCAN_N + SCAN_TILE - 1) / SCAN_TILE)   // 37

// Phase A1: per-block histogram over super-buckets.
__global__ __launch_bounds__(BIN_THREADS) void count_kernel(
    const int* __restrict__ rows,
    const int* __restrict__ cols,
    int* __restrict__ counts)     // [SCAN_N], counts[sb*NB + blk]
{
    __shared__ int cnt[NSB];
    for (int i = threadIdx.x; i < NSB; i += BIN_THREADS) cnt[i] = 0;
    __syncthreads();

    const int e0 = blockIdx.x * EPB;
    for (int e = e0 + (int)threadIdx.x; e < e0 + EPB; e += BIN_THREADS) {
        const int r = rows[e];
        const int c = N_USER + cols[e];
        atomicAdd(&cnt[r >> SB_SHIFT], 1);
        atomicAdd(&cnt[c >> SB_SHIFT], 1);
    }
    __syncthreads();

    for (int i = threadIdx.x; i < NSB; i += BIN_THREADS)
        counts[i * NB + blockIdx.x] = cnt[i];
    if (blockIdx.x == 0 && threadIdx.x == 0) counts[NSB * NB] = 0;  // sentinel
}

// ---------------------------------------------------------------------------
// Hierarchical exclusive scan: K1 per-tile scan + totals, K2 scan totals,
// K3 add tile bases. Replaces the 147-chunk serial single-block scan.
// ---------------------------------------------------------------------------
__global__ __launch_bounds__(1024) void scan_local_kernel(
    int* __restrict__ data, int n, int* __restrict__ totals)
{
    __shared__ int wsum[16];
    __shared__ int woff[16];
    const int tid  = threadIdx.x;
    const int lane = tid & 63;
    const int wid  = tid >> 6;
    const int idx  = blockIdx.x * SCAN_TILE + tid * 4;

    int v0 = 0, v1 = 0, v2 = 0, v3 = 0;
    if (idx + 3 < n) {
        int4 t = *reinterpret_cast<const int4*>(data + idx);
        v0 = t.x; v1 = t.y; v2 = t.z; v3 = t.w;
    } else {
        if (idx     < n) v0 = data[idx];
        if (idx + 1 < n) v1 = data[idx + 1];
        if (idx + 2 < n) v2 = data[idx + 2];
        if (idx + 3 < n) v3 = data[idx + 3];
    }
    const int tsum = v0 + v1 + v2 + v3;

    int incl = tsum;
    #pragma unroll
    for (int off = 1; off < 64; off <<= 1) {
        int t = __shfl_up(incl, off, 64);
        if (lane >= off) incl += t;
    }
    if (lane == 63) wsum[wid] = incl;
    __syncthreads();

    if (tid == 0) {
        int s = 0;
        #pragma unroll
        for (int w = 0; w < 16; ++w) { woff[w] = s; s += wsum[w]; }
        totals[blockIdx.x] = s;
    }
    __syncthreads();

    const int e0 = woff[wid] + incl - tsum;   // exclusive prefix of this thread
    const int e1 = e0 + v0;
    const int e2 = e1 + v1;
    const int e3 = e2 + v2;
    if (idx + 3 < n) {
        *reinterpret_cast<int4*>(data + idx) = make_int4(e0, e1, e2, e3);
    } else {
        if (idx     < n) data[idx]     = e0;
        if (idx + 1 < n) data[idx + 1] = e1;
        if (idx + 2 < n) data[idx + 2] = e2;
        if (idx + 3 < n) data[idx + 3] = e3;
    }
}

__global__ __launch_bounds__(64) void scan_totals_kernel(int* __restrict__ totals, int n)
{
    const int lane = threadIdx.x;
    int v = (lane < n) ? totals[lane] : 0;
    int incl = v;
    #pragma unroll
    for (int off = 1; off < 64; off <<= 1) {
        int t = __shfl_up(incl, off, 64);
        if (lane >= off) incl += t;
    }
    if (lane < n) totals[lane] = incl - v;    // exclusive
}

__global__ __launch_bounds__(256) void scan_add_kernel(
    int* __restrict__ data, int n, const int* __restrict__ totals)
{
    const int idx = (blockIdx.x * 256 + threadIdx.x) * 4;
    if (idx >= n) return;
    const int add = totals[idx >> 12];        // SCAN_TILE = 4096
    if (idx + 3 < n) {
        int4 t = *reinterpret_cast<const int4*>(data + idx);
        *reinterpret_cast<int4*>(data + idx) =
            make_int4(t.x + add, t.y + add, t.z + add, t.w + add);
    } else {
        for (int j = 0; j < 4 && idx + j < n; ++j) data[idx + j] += add;
    }
}

// Phase A3: deterministic scatter into super-bucket-grouped order.
// Record: x = (node_low8 << 18) | src   (src < 150000 < 2^18), y = val bits.
__global__ __launch_bounds__(BIN_THREADS) void bin2_kernel(
    const int* __restrict__ rows,
    const int* __restrict__ cols,
    const float* __restrict__ vals,
    const int* __restrict__ base,   // scanned counts: base[sb*NB + blk]
    int2* __restrict__ binned)      // [TOTAL_EDGES]
{
    __shared__ int cur[NSB];
    for (int i = threadIdx.x; i < NSB; i += BIN_THREADS)
        cur[i] = base[i * NB + blockIdx.x];
    __syncthreads();

    const int e0 = blockIdx.x * EPB;
    for (int e = e0 + (int)threadIdx.x; e < e0 + EPB; e += BIN_THREADS) {
        const int r  = rows[e];
        const int c  = N_USER + cols[e];
        const int vb = __float_as_int(vals[e]);
        // user row r gathers from item node c
        int p1 = atomicAdd(&cur[r >> SB_SHIFT], 1);
        binned[p1] = make_int2(((r & (NODES_PER_SB - 1)) << 18) | c, vb);
        // item row c gathers from user node r
        int p2 = atomicAdd(&cur[c >> SB_SHIFT], 1);
        binned[p2] = make_int2(((c & (NODES_PER_SB - 1)) << 18) | r, vb);
    }
}

// Phase B: per-super-bucket local sort to (node, src_bucket) granularity.
// One block per sb (~22K records, ~350KB window, L2-resident). Writes per-node
// CSR offsets; each node's list ends up src-bucket-ordered (temporal banding).
__global__ __launch_bounds__(1024) void fine_scatter_kernel(
    const int* __restrict__ base,    // [SCAN_N] scanned
    const int2* __restrict__ binned,
    int* __restrict__ offsets,       // [N_NODES + 1]
    int2* __restrict__ edges)        // [TOTAL_EDGES] final (src, val)
{
    const int b   = blockIdx.x;
    const int tid = threadIdx.x;
    const int s0  = base[b * NB];
    const int s1  = base[(b + 1) * NB];   // sentinel makes this valid for last b

    __shared__ int cnt[NKEY];
    __shared__ int ofs[NKEY];
    for (int k = tid; k < NKEY; k += 1024) cnt[k] = 0;
    __syncthreads();

    for (int i = s0 + tid; i < s1; i += 1024) {
        const int x   = binned[i].x;
        const int key = (x >> 18) * NBK + ((x & 0x3FFFF) >> SRC_BK_SHIFT);
        atomicAdd(&cnt[key], 1);
    }
    __syncthreads();

    // exclusive scan of cnt[0..NKEY) by wave 0 (NKEY/64 = 40 per lane)
    if (tid < 64) {
        int s = 0;
        for (int j = 0; j < NKEY / 64; ++j) s += cnt[tid * (NKEY / 64) + j];
        int incl = s;
        #pragma unroll
        for (int off = 1; off < 64; off <<= 1) {
            int t = __shfl_up(incl, off, 64);
            if (tid >= off) incl += t;
        }
        int run = incl - s;
        for (int j = 0; j < NKEY / 64; ++j) {
            const int k = tid * (NKEY / 64) + j;
            const int v = cnt[k];
            ofs[k] = run;
            run += v;
        }
    }
    __syncthreads();

    if (tid < NODES_PER_SB) {
        const int node = b * NODES_PER_SB + tid;
        if (node < N_NODES) offsets[node] = s0 + ofs[tid * NBK];
    }
    if (b == (int)gridDim.x - 1 && tid == 0) offsets[N_NODES] = TOTAL_EDGES;

    // reset cursors
    for (int k = tid; k < NKEY; k += 1024) cnt[k] = ofs[k];
    __syncthreads();

    // second read hits L2 (this block just fetched the window)
    for (int i = s0 + tid; i < s1; i += 1024) {
        int2 rec = binned[i];
        const int src = rec.x & 0x3FFFF;
        const int key = (rec.x >> 18) * NBK + (src >> SRC_BK_SHIFT);
        const int p   = s0 + atomicAdd(&cnt[key], 1);
        edges[p] = make_int2(src, rec.y);
    }
}

// ---------------------------------------------------------------------------
// Gather propagation: one wave per output row, lane = dim. Fused residual.
// Edge tile (64 edges) loaded coalesced, broadcast via shfl; 16 independent
// row-gathers in flight per step. Non-temporal on streams to protect L2.
// ---------------------------------------------------------------------------
__global__ __launch_bounds__(256) void gather_kernel(
    const int* __restrict__ offsets,
    const int2* __restrict__ edges,
    const float* __restrict__ lat_prev,
    float* __restrict__ gcn_l,
    float* __restrict__ lat_l)
{
    const int gtid = blockIdx.x * blockDim.x + threadIdx.x;
    const int node = gtid >> 6;
    const int lane = gtid & 63;
    if (node >= N_NODES) return;

    const int beg = offsets[node];
    const int end = offsets[node + 1];
    const long long* ep = reinterpret_cast<const long long*>(edges);

    float acc = 0.f;
    for (int t = beg; t < end; t += 64) {
        const int idx = t + lane;
        long long my = (idx < end) ? __builtin_nontemporal_load(ep + idx) : 0LL;
        const int m = min(64, end - t);
        int k = 0;
        for (; k + 16 <= m; k += 16) {
            long long p0  = __shfl(my, k + 0);
            long long p1  = __shfl(my, k + 1);
            long long p2  = __shfl(my, k + 2);
            long long p3  = __shfl(my, k + 3);
            long long p4  = __shfl(my, k + 4);
            long long p5  = __shfl(my, k + 5);
            long long p6  = __shfl(my, k + 6);
            long long p7  = __shfl(my, k + 7);
            long long p8  = __shfl(my, k + 8);
            long long p9  = __shfl(my, k + 9);
            long long p10 = __shfl(my, k + 10);
            long long p11 = __shfl(my, k + 11);
            long long p12 = __shfl(my, k + 12);
            long long p13 = __shfl(my, k + 13);
            long long p14 = __shfl(my, k + 14);
            long long p15 = __shfl(my, k + 15);
            float x0  = lat_prev[(((int)p0)  << 6) | lane];
            float x1  = lat_prev[(((int)p1)  << 6) | lane];
            float x2  = lat_prev[(((int)p2)  << 6) | lane];
            float x3  = lat_prev[(((int)p3)  << 6) | lane];
            float x4  = lat_prev[(((int)p4)  << 6) | lane];
            float x5  = lat_prev[(((int)p5)  << 6) | lane];
            float x6  = lat_prev[(((int)p6)  << 6) | lane];
            float x7  = lat_prev[(((int)p7)  << 6) | lane];
            float x8  = lat_prev[(((int)p8)  << 6) | lane];
            float x9  = lat_prev[(((int)p9)  << 6) | lane];
            float x10 = lat_prev[(((int)p10) << 6) | lane];
            float x11 = lat_prev[(((int)p11) << 6) | lane];
            float x12 = lat_prev[(((int)p12) << 6) | lane];
            float x13 = lat_prev[(((int)p13) << 6) | lane];
            float x14 = lat_prev[(((int)p14) << 6) | lane];
            float x15 = lat_prev[(((int)p15) << 6) | lane];
            acc += __int_as_float((int)(p0  >> 32)) * x0;
            acc += __int_as_float((int)(p1  >> 32)) * x1;
            acc += __int_as_float((int)(p2  >> 32)) * x2;
            acc += __int_as_float((int)(p3  >> 32)) * x3;
            acc += __int_as_float((int)(p4  >> 32)) * x4;
            acc += __int_as_float((int)(p5  >> 32)) * x5;
            acc += __int_as_float((int)(p6  >> 32)) * x6;
            acc += __int_as_float((int)(p7  >> 32)) * x7;
            acc += __int_as_float((int)(p8  >> 32)) * x8;
            acc += __int_as_float((int)(p9  >> 32)) * x9;
            acc += __int_as_float((int)(p10 >> 32)) * x10;
            acc += __int_as_float((int)(p11 >> 32)) * x11;
            acc += __int_as_float((int)(p12 >> 32)) * x12;
            acc += __int_as_float((int)(p13 >> 32)) * x13;
            acc += __int_as_float((int)(p14 >> 32)) * x14;
            acc += __int_as_float((int)(p15 >> 32)) * x15;
        }
        for (; k + 8 <= m; k += 8) {
            long long p0 = __shfl(my, k + 0);
            long long p1 = __shfl(my, k + 1);
            long long p2 = __shfl(my, k + 2);
            long long p3 = __shfl(my, k + 3);
            long long p4 = __shfl(my, k + 4);
            long long p5 = __shfl(my, k + 5);
            long long p6 = __shfl(my, k + 6);
            long long p7 = __shfl(my, k + 7);
            float x0 = lat_prev[(((int)p0) << 6) | lane];
            float x1 = lat_prev[(((int)p1) << 6) | lane];
            float x2 = lat_prev[(((int)p2) << 6) | lane];
            float x3 = lat_prev[(((int)p3) << 6) | lane];
            float x4 = lat_prev[(((int)p4) << 6) | lane];
            float x5 = lat_prev[(((int)p5) << 6) | lane];
            float x6 = lat_prev[(((int)p6) << 6) | lane];
            float x7 = lat_prev[(((int)p7) << 6) | lane];
            acc += __int_as_float((int)(p0 >> 32)) * x0;
            acc += __int_as_float((int)(p1 >> 32)) * x1;
            acc += __int_as_float((int)(p2 >> 32)) * x2;
            acc += __int_as_float((int)(p3 >> 32)) * x3;
            acc += __int_as_float((int)(p4 >> 32)) * x4;
            acc += __int_as_float((int)(p5 >> 32)) * x5;
            acc += __int_as_float((int)(p6 >> 32)) * x6;
            acc += __int_as_float((int)(p7 >> 32)) * x7;
        }
        for (; k < m; ++k) {
            long long p = __shfl(my, k);
            acc += __int_as_float((int)(p >> 32)) * lat_prev[(((int)p) << 6) | lane];
        }
    }

    // o = node*64 + lane == gtid
    const int o = gtid;
    __builtin_nontemporal_store(acc, &gcn_l[o]);
    __builtin_nontemporal_store(lat_prev[o] + acc, &lat_l[o]);
}

// ---------------------------------------------------------------------------
// Fallback tier 2: single-pass CSR build (global random scatter fill)
// ---------------------------------------------------------------------------
__global__ __launch_bounds__(256) void histogram_kernel(
    const int* __restrict__ rows,
    const int* __restrict__ cols,
    int* __restrict__ counts)
{
    int e = blockIdx.x * blockDim.x + threadIdx.x;
    if (e >= N_NNZ) return;
    atomicAdd(&counts[rows[e]], 1);
    atomicAdd(&counts[N_USER + cols[e]], 1);
}

__global__ __launch_bounds__(1024) void scan_kernel(int* __restrict__ data, int n)
{
    __shared__ int wsum[16];
    __shared__ int woff[16];
    __shared__ int carry_s;
    if (threadIdx.x == 0) carry_s = 0;
    __syncthreads();

    const int lane = threadIdx.x & 63;
    const int wid  = threadIdx.x >> 6;

    for (int base = 0; base < n; base += 1024) {
        int i = base + (int)threadIdx.x;
        int v = (i < n) ? data[i] : 0;

        int incl = v;
        #pragma unroll
        for (int off = 1; off < 64; off <<= 1) {
            int t = __shfl_up(incl, off, 64);
            if (lane >= off) incl += t;
        }
        if (lane == 63) wsum[wid] = incl;
        __syncthreads();

        if (threadIdx.x == 0) {
            int s = carry_s;
            #pragma unroll
            for (int w = 0; w < 16; ++w) { woff[w] = s; s += wsum[w]; }
            carry_s = s;
        }
        __syncthreads();

        if (i < n) data[i] = woff[wid] + incl - v;
        __syncthreads();
    }
}

__global__ __launch_bounds__(256) void fill_kernel(
    const int* __restrict__ rows,
    const int* __restrict__ cols,
    const float* __restrict__ vals,
    int* __restrict__ cursor,
    int2* __restrict__ edges)
{
    int e = blockIdx.x * blockDim.x + threadIdx.x;
    if (e >= N_NNZ) return;
    const int r = rows[e];
    const int c = cols[e];
    const int vb = __float_as_int(vals[e]);
    int pu = atomicAdd(&cursor[r], 1);
    edges[pu] = make_int2(N_USER + c, vb);
    int pi = atomicAdd(&cursor[N_USER + c], 1);
    edges[pi] = make_int2(r, vb);
}

// ---------------------------------------------------------------------------
// Fallback tier 3: atomic scatter
// ---------------------------------------------------------------------------
__global__ __launch_bounds__(256) void scatter_kernel(
    const int* __restrict__ rows,
    const int* __restrict__ cols,
    const float* __restrict__ vals,
    const float* __restrict__ lat_prev,
    float* __restrict__ gcn_out)
{
    const int gtid = blockIdx.x * blockDim.x + threadIdx.x;
    const int edge = gtid >> 6;
    const int lane = gtid & 63;
    if (edge >= N_NNZ) return;
    const int r = rows[edge];
    const int c = cols[edge];
    const float v = vals[edge];
    atomicAdd(&gcn_out[(size_t)r * DIM + lane],
              v * lat_prev[(size_t)(N_USER + c) * DIM + lane]);
    atomicAdd(&gcn_out[(size_t)(N_USER + c) * DIM + lane],
              v * lat_prev[(size_t)r * DIM + lane]);
}

__global__ __launch_bounds__(256) void residual_add_kernel(
    const float4* __restrict__ a,
    const float4* __restrict__ b,
    float4* __restrict__ out,
    int n4)
{
    int i = blockIdx.x * blockDim.x + threadIdx.x;
    if (i < n4) {
        float4 av = a[i], bv = b[i];
        out[i] = make_float4(av.x + bv.x, av.y + bv.y, av.z + bv.z, av.w + bv.w);
    }
}

extern "C" void kernel_launch(void* const* d_in, const int* in_sizes, int n_in,
                              void* d_out, int out_size, void* d_ws, size_t ws_size,
                              hipStream_t stream) {
    const int*   rows   = (const int*)d_in[0];
    const int*   cols   = (const int*)d_in[1];
    const float* vals   = (const float*)d_in[2];
    const float* embeds = (const float*)d_in[3];

    float* out = (float*)d_out;
    const size_t N = (size_t)N_NODES * DIM;   // floats per snapshot

    float* lats = out;            // [4][N_NODES][DIM]
    float* gcn  = out + 4 * N;    // [4][N_NODES][DIM]

    // lats[0] = gcn[0] = embeds
    hipMemcpyAsync(lats, embeds, N * sizeof(float), hipMemcpyDeviceToDevice, stream);
    hipMemcpyAsync(gcn,  embeds, N * sizeof(float), hipMemcpyDeviceToDevice, stream);

    const size_t edges_bytes = (size_t)TOTAL_EDGES * sizeof(int2);   // 102,400,000

    // ---- Tier-1 workspace layout: segmented counting sort ----
    const size_t mat_bytes   = (size_t)SCAN_N * sizeof(int);                 // 600,068
    const size_t offs_off    = (mat_bytes + 15) & ~(size_t)15;
    const size_t offs_bytes  = (size_t)(N_NODES + 1) * sizeof(int);          // 600,004
    const size_t tot_off     = (offs_off + offs_bytes + 15) & ~(size_t)15;
    const size_t tot_bytes   = (size_t)NSCAN * sizeof(int);
    const size_t binned_off  = (tot_off + tot_bytes + 15) & ~(size_t)15;
    const size_t edges2_off  = (binned_off + edges_bytes + 15) & ~(size_t)15;
    const size_t need_sort   = edges2_off + edges_bytes;                     // ~206 MB

    // ---- Tier-2 workspace layout ----
    const size_t t2_off_bytes    = (size_t)(N_NODES + 1) * sizeof(int);
    const size_t t2_cursor_off   = (t2_off_bytes + 15) & ~(size_t)15;
    const size_t t2_cursor_bytes = (size_t)N_NODES * sizeof(int);
    const size_t t2_edges_off    = (t2_cursor_off + t2_cursor_bytes + 15) & ~(size_t)15;
    const size_t need_old        = t2_edges_off + edges_bytes;               // ~104 MB

    const int eb = (N_NNZ + 255) / 256;
    const int gb = (N_NODES * 64 + 255) / 256;

    if (ws_size >= need_sort) {
        int*  mat     = (int*)d_ws;                       // counts -> scanned bases
        int*  offsets = (int*)((char*)d_ws + offs_off);
        int*  totals  = (int*)((char*)d_ws + tot_off);
        int2* binned  = (int2*)((char*)d_ws + binned_off);
        int2* edges   = (int2*)((char*)d_ws + edges2_off);

        count_kernel<<<NB, BIN_THREADS, 0, stream>>>(rows, cols, mat);
        scan_local_kernel<<<NSCAN, 1024, 0, stream>>>(mat, SCAN_N, totals);
        scan_totals_kernel<<<1, 64, 0, stream>>>(totals, NSCAN);
        scan_add_kernel<<<(SCAN_N + 1023) / 1024, 256, 0, stream>>>(mat, SCAN_N, totals);
        bin2_kernel<<<NB, BIN_THREADS, 0, stream>>>(rows, cols, vals, mat, binned);
        fine_scatter_kernel<<<NSB, 1024, 0, stream>>>(mat, binned, offsets, edges);

        for (int l = 1; l <= N_LAYER; ++l) {
            const float* lat_prev = lats + (size_t)(l - 1) * N;
            gather_kernel<<<gb, 256, 0, stream>>>(
                offsets, edges, lat_prev,
                gcn  + (size_t)l * N,
                lats + (size_t)l * N);
        }
    } else if (ws_size >= need_old) {
        int*  offsets = (int*)d_ws;
        int*  cursor  = (int*)((char*)d_ws + t2_cursor_off);
        int2* edges   = (int2*)((char*)d_ws + t2_edges_off);

        hipMemsetAsync(offsets, 0, t2_off_bytes, stream);
        histogram_kernel<<<eb, 256, 0, stream>>>(rows, cols, offsets);
        scan_kernel<<<1, 1024, 0, stream>>>(offsets, N_NODES + 1);
        hipMemcpyAsync(cursor, offsets, t2_cursor_bytes, hipMemcpyDeviceToDevice, stream);
        fill_kernel<<<eb, 256, 0, stream>>>(rows, cols, vals, cursor, edges);

        for (int l = 1; l <= N_LAYER; ++l) {
            const float* lat_prev = lats + (size_t)(l - 1) * N;
            gather_kernel<<<gb, 256, 0, stream>>>(
                offsets, edges, lat_prev,
                gcn  + (size_t)l * N,
                lats + (size_t)l * N);
        }
    } else {
        hipMemsetAsync(gcn + N, 0, 3 * N * sizeof(float), stream);
        const int scatter_blocks = (N_NNZ * 64 + 255) / 256;
        const int n4 = (int)(N / 4);
        const int add_blocks = (n4 + 255) / 256;
        for (int l = 1; l <= N_LAYER; ++l) {
            const float* lat_prev = lats + (size_t)(l - 1) * N;
            float* gcn_l = gcn  + (size_t)l * N;
            float* lat_l = lats + (size_t)l * N;
            scatter_kernel<<<scatter_blocks, 256, 0, stream>>>(
                rows, cols, vals, lat_prev, gcn_l);
            residual_add_kernel<<<add_blocks, 256, 0, stream>>>(
                (const float4*)lat_prev, (const float4*)gcn_l, (float4*)lat_l, n4);
        }
    }
}